// Round 19
// baseline (267.763 us; speedup 1.0000x reference)
//
#include <hip/hip_runtime.h>
#include <math.h>

#define BB 16
#define SS 256
#define FF 512
#define EE 128
#define HH 64
#define GG 192  // 3H
#define LL 8
#define TT 16   // scan tile count (SS/16)

typedef __fp16 f16x2 __attribute__((ext_vector_type(2)));
typedef _Float16 f16x8 __attribute__((ext_vector_type(8)));
typedef float f32x4v __attribute__((ext_vector_type(4)));

__device__ __forceinline__ float sigmoid_f(float x) {
    return 1.0f / (1.0f + __expf(-x));
}
__device__ __forceinline__ float tanh_f(float x) {
    return 1.0f - 2.0f / (1.0f + __expf(2.0f * x));
}

// ---------------------------------------------------------------------------
// Generic C[m,n] = sum_k A[m,k] * Bm[n,k] + bias[n]
// ---------------------------------------------------------------------------
__device__ __forceinline__ void gemm_bt_body(
    const float* __restrict__ A, const float* __restrict__ Bm,
    const float* __restrict__ bias, float* __restrict__ C,
    int N, int K)
{
    __shared__ float As[32][68];
    __shared__ float Bs[64][68];
    const int t = threadIdx.x;
    const int row0 = blockIdx.x * 32;
    const int col0 = blockIdx.y * 64;
    const int tr = t & 7;
    const int tc = t >> 3;
    float acc[4][2] = {{0.f,0.f},{0.f,0.f},{0.f,0.f},{0.f,0.f}};

    for (int k0 = 0; k0 < K; k0 += 64) {
        {
            int r = t >> 3;
            int q = t & 7;
            const float* src = &A[(size_t)(row0 + r) * K + k0];
            #pragma unroll
            for (int it = 0; it < 2; ++it) {
                int kk = (q + it * 8) * 4;
                *(float4*)&As[r][kk] = *(const float4*)&src[kk];
            }
        }
        {
            int r = t >> 2;
            int q = t & 3;
            int n = col0 + r;
            #pragma unroll
            for (int it = 0; it < 4; ++it) {
                int kk = (q + it * 4) * 4;
                float4 v = {0.f, 0.f, 0.f, 0.f};
                if (n < N) v = *(const float4*)&Bm[(size_t)n * K + k0 + kk];
                *(float4*)&Bs[r][kk] = v;
            }
        }
        __syncthreads();
        #pragma unroll
        for (int k = 0; k < 64; k += 4) {
            float4 av[4], bv[2];
            #pragma unroll
            for (int i = 0; i < 4; ++i) av[i] = *(const float4*)&As[tr + 8*i][k];
            #pragma unroll
            for (int j = 0; j < 2; ++j) bv[j] = *(const float4*)&Bs[tc + 32*j][k];
            #pragma unroll
            for (int i = 0; i < 4; ++i)
                #pragma unroll
                for (int j = 0; j < 2; ++j)
                    acc[i][j] += av[i].x*bv[j].x + av[i].y*bv[j].y
                               + av[i].z*bv[j].z + av[i].w*bv[j].w;
        }
        __syncthreads();
    }

    #pragma unroll
    for (int i = 0; i < 4; ++i) {
        int r = row0 + tr + 8*i;
        #pragma unroll
        for (int j = 0; j < 2; ++j) {
            int c = col0 + tc + 32*j;
            if (c < N) C[(size_t)r * N + c] = acc[i][j] + bias[c];
        }
    }
}

__global__ __launch_bounds__(256) void gemm_bt(
    const float* __restrict__ A, const float* __restrict__ Bm,
    const float* __restrict__ bias, float* __restrict__ C,
    int N, int K)
{
    gemm_bt_body(A, Bm, bias, C, N, K);
}

__global__ __launch_bounds__(256) void gemm_bt_dual(
    const float* __restrict__ A,
    const float* __restrict__ B0, const float* __restrict__ bias0, float* __restrict__ C0,
    const float* __restrict__ B1, const float* __restrict__ bias1, float* __restrict__ C1,
    int N, int K)
{
    const float* Bm   = blockIdx.z ? B1    : B0;
    const float* bias = blockIdx.z ? bias1 : bias0;
    float*       C    = blockIdx.z ? C1    : C0;
    gemm_bt_body(A, Bm, bias, C, N, K);
}

// ---------------------------------------------------------------------------
// GRU scan (r19): MFMA-batched. One block per GRU (grid=2, 256 thr, 4 waves).
// Per step: gh[192,16] = Whh[192,64] . h[64,16] as 12 16x16 tiles, K=64.
// Wave w owns tiles {w, 4+w, 8+w} (r,z,n slices for units 16w..16w+16) -> 6
// MFMA/wave/step (v_mfma_f32_16x16x32_f16, K split 2x32). A-frags (Whh) are
// STATIONARY: loaded once, cvt to f16, 24 VGPRs. xp + bias fold into the
// MFMA C-init. D layout (verified): col=lane&15=batch, row=(lane>>4)*4+reg
// = unit-in-tile -> r,z,n for one (batch,unit) in the SAME lane; 4 gate
// updates/lane/step. h exchange: 1 ds_write_b128 + lgkm-barrier + 4
// ds_read_b128 + 8 cvt_pkrtz (double-buffered h_lds[2][16][68]).
// A/B k-order only needs self-consistency (dot permutation-invariant).
// f16 weight/h quantization = r16's measured absmax 0.0156 << 0.24.
// Replaces the scalar 3-wave GRU stuck at ~1019 cyc/step (r2-r18 verdict).
// ---------------------------------------------------------------------------
__global__ __launch_bounds__(256, 1)
void gru_mfma_kernel(
    const float* __restrict__ xpa, const float* __restrict__ xpb,
    const float* __restrict__ Whh_a, const float* __restrict__ bhh_a,
    const float* __restrict__ Whh_b, const float* __restrict__ bhh_b,
    float* __restrict__ hs_a, float* __restrict__ hs_b)
{
    const int which = blockIdx.x;    // 0 = alpha, 1 = beta
    const float* xp  = which ? xpb   : xpa;
    const float* Whh = which ? Whh_b : Whh_a;
    const float* bhh = which ? bhh_b : bhh_a;
    float* hs        = which ? hs_b  : hs_a;

    const int t = threadIdx.x;
    const int w = t >> 6;            // wave 0..3: owns units 16w..16w+16
    const int l = t & 63;
    const int lo = l & 15;           // A-row within tile / B,C,D col (=batch)
    const int hi = l >> 4;           // 0..3
    const int u0 = 16 * w + 4 * hi;  // C/D unit base (rows hi*4+reg)
    const int kA = hi * 8;           // A/B k base within 32-slice

    __shared__ float h_lds[2][16][68];

#define BCU(x) __builtin_bit_cast(unsigned, (x))
#define PK8(dst, a, b)                                                        \
    {                                                                         \
        f16x2 p0_ = __builtin_amdgcn_cvt_pkrtz((a).x, (a).y);                 \
        f16x2 p1_ = __builtin_amdgcn_cvt_pkrtz((a).z, (a).w);                 \
        f16x2 p2_ = __builtin_amdgcn_cvt_pkrtz((b).x, (b).y);                 \
        f16x2 p3_ = __builtin_amdgcn_cvt_pkrtz((b).z, (b).w);                 \
        uint4 U_ = {BCU(p0_), BCU(p1_), BCU(p2_), BCU(p3_)};                  \
        dst = __builtin_bit_cast(f16x8, U_);                                  \
    }

    // Stationary A-frags: gate g, k-slice ks: row = g*64 + 16w + lo,
    // k = kA + i + 32*ks (i = 0..7).
    f16x8 AR0, AR1, AZ0, AZ1, AN0, AN1;
    {
        const float* r_ = &Whh[(size_t)(0 * 64 + 16 * w + lo) * HH + kA];
        const float* z_ = &Whh[(size_t)(1 * 64 + 16 * w + lo) * HH + kA];
        const float* n_ = &Whh[(size_t)(2 * 64 + 16 * w + lo) * HH + kA];
        float4 a0, a1;
        a0 = *(const float4*)&r_[0];  a1 = *(const float4*)&r_[4];  PK8(AR0, a0, a1);
        a0 = *(const float4*)&r_[32]; a1 = *(const float4*)&r_[36]; PK8(AR1, a0, a1);
        a0 = *(const float4*)&z_[0];  a1 = *(const float4*)&z_[4];  PK8(AZ0, a0, a1);
        a0 = *(const float4*)&z_[32]; a1 = *(const float4*)&z_[36]; PK8(AZ1, a0, a1);
        a0 = *(const float4*)&n_[0];  a1 = *(const float4*)&n_[4];  PK8(AN0, a0, a1);
        a0 = *(const float4*)&n_[32]; a1 = *(const float4*)&n_[36]; PK8(AN1, a0, a1);
    }

    // Biases for this lane's 4 output units.
    const float4 brv = *(const float4*)&bhh[0 * 64 + u0];
    const float4 bzv = *(const float4*)&bhh[1 * 64 + u0];
    const float4 bnv = *(const float4*)&bhh[2 * 64 + u0];

    const float* xbase = xp + (size_t)lo * SS * GG;   // batch = lo

    // step-0 xp
    float4 xr = *(const float4*)&xbase[0 * 64 + u0];
    float4 xz = *(const float4*)&xbase[1 * 64 + u0];
    float4 xn = *(const float4*)&xbase[2 * 64 + u0];

    uint4 z4 = {0u, 0u, 0u, 0u};
    f16x8 Bf0 = __builtin_bit_cast(f16x8, z4);
    f16x8 Bf1 = __builtin_bit_cast(f16x8, z4);
    float4 hc = {0.f, 0.f, 0.f, 0.f};

    for (int s = 0; s < SS; ++s) {
        // prefetch next step's xp (last iter over-reads into adjacent
        // workspace region — allocated, value discarded)
        const float* nx = xbase + (size_t)(s + 1) * GG;
        float4 nxr = *(const float4*)&nx[0 * 64 + u0];
        float4 nxz = *(const float4*)&nx[1 * 64 + u0];
        float4 nxn = *(const float4*)&nx[2 * 64 + u0];

        f32x4v accR, accZ, accN;
        accR[0] = brv.x + xr.x; accR[1] = brv.y + xr.y;
        accR[2] = brv.z + xr.z; accR[3] = brv.w + xr.w;
        accZ[0] = bzv.x + xz.x; accZ[1] = bzv.y + xz.y;
        accZ[2] = bzv.z + xz.z; accZ[3] = bzv.w + xz.w;
        accN[0] = bnv.x; accN[1] = bnv.y; accN[2] = bnv.z; accN[3] = bnv.w;

        accR = __builtin_amdgcn_mfma_f32_16x16x32_f16(AR0, Bf0, accR, 0, 0, 0);
        accR = __builtin_amdgcn_mfma_f32_16x16x32_f16(AR1, Bf1, accR, 0, 0, 0);
        accZ = __builtin_amdgcn_mfma_f32_16x16x32_f16(AZ0, Bf0, accZ, 0, 0, 0);
        accZ = __builtin_amdgcn_mfma_f32_16x16x32_f16(AZ1, Bf1, accZ, 0, 0, 0);
        accN = __builtin_amdgcn_mfma_f32_16x16x32_f16(AN0, Bf0, accN, 0, 0, 0);
        accN = __builtin_amdgcn_mfma_f32_16x16x32_f16(AN1, Bf1, accN, 0, 0, 0);

#define GATEUP(idx, F)                                                        \
        {                                                                     \
            float r_ = sigmoid_f(accR[idx]);                                  \
            float z_ = sigmoid_f(accZ[idx]);                                  \
            float n_ = tanh_f(xn.F + r_ * accN[idx]);                         \
            hc.F = fmaf(z_, hc.F - n_, n_);                                   \
        }
        GATEUP(0, x) GATEUP(1, y) GATEUP(2, z) GATEUP(3, w)
#undef GATEUP

        // write h out (batch = lo, units u0..u0+3)
        *(float4*)&hs[((size_t)lo * SS + s) * HH + u0] = hc;

        // exchange h through double-buffered LDS (lgkm-only barrier)
        *(float4*)&h_lds[s & 1][lo][u0] = hc;
        asm volatile("s_waitcnt lgkmcnt(0)" ::: "memory");
        __builtin_amdgcn_s_barrier();
        asm volatile("" ::: "memory");

        // rebuild B-frags for next step: B[k][col=lo], k = kA+i (+32)
        const float* hb = &h_lds[s & 1][lo][0];
        float4 f0 = *(const float4*)&hb[kA];
        float4 f1 = *(const float4*)&hb[kA + 4];
        float4 f2 = *(const float4*)&hb[kA + 32];
        float4 f3 = *(const float4*)&hb[kA + 36];
        PK8(Bf0, f0, f1);
        PK8(Bf1, f2, f3);

        xr = nxr; xz = nxz; xn = nxn;
    }
#undef PK8
#undef BCU
}

// ---------------------------------------------------------------------------
// FUSED attn_val + scanA. One block per (batch, 16-row tile).
// ---------------------------------------------------------------------------
__global__ __launch_bounds__(128) void attn_scanA_kernel(
    const float* __restrict__ h_alpha, const float* __restrict__ h_beta,
    const float* __restrict__ emb, const float* __restrict__ M,
    const float* __restrict__ Wa, const float* __restrict__ ba,
    const float* __restrict__ Wb, const float* __restrict__ bb,
    float* __restrict__ val, float* __restrict__ wj,
    float* __restrict__ tsum, float* __restrict__ wsum)
{
    const int b = blockIdx.x, tt = blockIdx.y;
    const int t = threadIdx.x;       // 0..127
    const int j0 = tt * 16;
    __shared__ float hb_s[HH];
    __shared__ float wj_s;

    const float bbt = bb[t];
    const float4* wrow = (const float4*)&Wb[(size_t)t * HH];

    float ts = 0.f;
    float ws = 0.f;

    for (int jj = 0; jj < 16; ++jj) {
        const int row = b * SS + j0 + jj;
        if (t < 64) {
            hb_s[t] = h_beta[(size_t)row * HH + t];
            float p = h_alpha[(size_t)row * HH + t] * Wa[t];
            #pragma unroll
            for (int off = 32; off > 0; off >>= 1) p += __shfl_down(p, off);
            if (t == 0) {
                float a = __expf(p + ba[0]) * M[row];
                wj_s = a;
                wj[row] = a;
            }
        }
        __syncthreads();

        float acc = bbt;
        #pragma unroll
        for (int k = 0; k < 16; ++k) {
            float4 w4 = wrow[k];
            float4 h4 = *(const float4*)&hb_s[k * 4];
            acc += w4.x*h4.x + w4.y*h4.y + w4.z*h4.z + w4.w*h4.w;
        }
        float v = tanh_f(acc) * emb[(size_t)row * EE + t] * wj_s;
        val[(size_t)row * EE + t] = v;
        ts += v;
        if (t == 0) ws += wj_s;
        __syncthreads();   // hb_s/wj_s reused next row
    }

    tsum[((size_t)(b * TT + tt)) * EE + t] = ts;
    if (t == 0) wsum[b * TT + tt] = ws;
}

// ---------------------------------------------------------------------------
// FUSED scanB + proj + cur-partial. One block per (batch, 16-row tile);
// wtd stays in LDS; each block atomicAdds its 16-row partial of
// cur_output[b,l] (out_cur zeroed by hipMemsetAsync before launch).
// ---------------------------------------------------------------------------
__global__ __launch_bounds__(128) void scanB_proj_kernel(
    const float* __restrict__ val, const float* __restrict__ wj,
    const float* __restrict__ tsum, const float* __restrict__ wsum,
    const float* __restrict__ Wp, const float* __restrict__ bp,
    const float* __restrict__ M, const float* __restrict__ curM,
    float* __restrict__ out, float* __restrict__ out_cur)
{
    const int b = blockIdx.x, tt = blockIdx.y;
    const int t = threadIdx.x;       // 0..127  (= e for the scan phase)
    const int j0 = tt * 16;

    __shared__ float wtd_s[16][132];
    __shared__ float wp_s[8][132];
    __shared__ float red_s[16][8];

    // beyond-tile suffix
    float se = 0.f;
    for (int t2 = tt + 1; t2 < TT; ++t2)
        se += tsum[((size_t)(b * TT + t2)) * EE + t];
    float d = 1e-10f;
    for (int t2 = tt + 1; t2 < TT; ++t2)
        d += wsum[b * TT + t2];

    // in-tile suffix (16 steps), results stay in LDS
    for (int jj = 15; jj >= 0; --jj) {
        size_t idx = ((size_t)(b * SS + j0 + jj)) * EE + t;
        se += val[idx];
        d += wj[b * SS + j0 + jj];
        wtd_s[jj][t] = se / d;
    }

    // stage Wp (8 x 128): 256 float4 total, 2 per thread
    #pragma unroll
    for (int it = 0; it < 2; ++it) {
        int idx = t + it * 128;      // 0..255
        int r = idx >> 5;            // 0..7
        int c = idx & 31;            // 0..31
        *(float4*)&wp_s[r][c * 4] = *(const float4*)&Wp[(size_t)r * EE + c * 4];
    }
    __syncthreads();

    // projection: thread = (row r, output l)
    const int r = t >> 3, l = t & 7;
    float acc = 0.f;
    #pragma unroll
    for (int i = 0; i < 32; ++i) {
        float4 a = *(const float4*)&wtd_s[r][i * 4];
        float4 w = *(const float4*)&wp_s[l][i * 4];
        acc += a.x*w.x + a.y*w.y + a.z*w.z + a.w*w.w;
    }
    const int row = b * SS + j0 + r;
    float ov = (acc + bp[l]) * M[row];
    out[(size_t)row * LL + l] = ov;

    // cur partial: sum over this tile's 16 rows for each l
    red_s[r][l] = ov * curM[row];
    __syncthreads();
    if (t < 8) {
        float sum = 0.f;
        #pragma unroll
        for (int r2 = 0; r2 < 16; ++r2) sum += red_s[r2][t];
        atomicAdd(&out_cur[b * LL + t], sum);
    }
}

// ---------------------------------------------------------------------------
extern "C" void kernel_launch(void* const* d_in, const int* in_sizes, int n_in,
                              void* d_out, int out_size, void* d_ws, size_t ws_size,
                              hipStream_t stream)
{
    const float* X       = (const float*)d_in[0];
    const float* M       = (const float*)d_in[1];
    const float* cur_M   = (const float*)d_in[2];
    const float* W_embed = (const float*)d_in[3];
    const float* b_embed = (const float*)d_in[4];
    const float* Wih_a   = (const float*)d_in[5];
    const float* Whh_a   = (const float*)d_in[6];
    const float* bih_a   = (const float*)d_in[7];
    const float* bhh_a   = (const float*)d_in[8];
    const float* Wih_b   = (const float*)d_in[9];
    const float* Whh_b   = (const float*)d_in[10];
    const float* bih_b   = (const float*)d_in[11];
    const float* bhh_b   = (const float*)d_in[12];
    const float* Wb      = (const float*)d_in[13];
    const float* bb      = (const float*)d_in[14];
    const float* Wa      = (const float*)d_in[15];
    const float* ba      = (const float*)d_in[16];
    const float* Wp      = (const float*)d_in[17];
    const float* bp      = (const float*)d_in[18];
    float* out = (float*)d_out;
    float* out_cur = out + (size_t)BB * SS * LL;

    float* ws  = (float*)d_ws;
    float* emb = ws;                          // B*S*E
    float* xpa = emb + (size_t)BB*SS*EE;      // B*S*192
    float* xpb = xpa + (size_t)BB*SS*GG;
    float* ha  = xpb + (size_t)BB*SS*GG;      // B*S*H
    float* hb  = ha  + (size_t)BB*SS*HH;
    float* val = hb  + (size_t)BB*SS*HH;      // B*S*E
    float* wjv = val + (size_t)BB*SS*EE;      // B*S
    float* tsum = wjv + (size_t)BB*SS;        // B*TT*E
    float* wsum = tsum + (size_t)BB*TT*EE;    // B*TT

    const int ROWS = BB * SS;                 // 4096

    hipMemsetAsync(out_cur, 0, (size_t)BB * LL * sizeof(float), stream);
    gemm_bt<<<dim3(ROWS/32, EE/64), 256, 0, stream>>>(X, W_embed, b_embed, emb, EE, FF);
    gemm_bt_dual<<<dim3(ROWS/32, (GG+63)/64, 2), 256, 0, stream>>>(
        emb, Wih_a, bih_a, xpa, Wih_b, bih_b, xpb, GG, EE);
    gru_mfma_kernel<<<2, 256, 0, stream>>>(
        xpa, xpb, Whh_a, bhh_a, Whh_b, bhh_b, ha, hb);
    attn_scanA_kernel<<<dim3(BB, TT), 128, 0, stream>>>(
        ha, hb, emb, M, Wa, ba, Wb, bb, val, wjv, tsum, wsum);
    scanB_proj_kernel<<<dim3(BB, TT), 128, 0, stream>>>(
        val, wjv, tsum, wsum, Wp, bp, M, cur_M, out, out_cur);
}

// Round 20
// 192.447 us; speedup vs baseline: 1.3914x; 1.3914x over previous
//
#include <hip/hip_runtime.h>
#include <hip/hip_fp16.h>
#include <math.h>

#define BB 16
#define SS 256
#define FF 512
#define EE 128
#define HH 64
#define GG 192  // 3H
#define LL 8
#define TT 16   // scan tile count (SS/16)

typedef __fp16 f16x2 __attribute__((ext_vector_type(2)));

__device__ __forceinline__ float sigmoid_f(float x) {
    return 1.0f / (1.0f + __expf(-x));
}
__device__ __forceinline__ float tanh_f(float x) {
    return 1.0f - 2.0f / (1.0f + __expf(2.0f * x));
}

// ---------------------------------------------------------------------------
// Generic C[m,n] = sum_k A[m,k] * Bm[n,k] + bias[n]
// ---------------------------------------------------------------------------
__device__ __forceinline__ void gemm_bt_body(
    const float* __restrict__ A, const float* __restrict__ Bm,
    const float* __restrict__ bias, float* __restrict__ C,
    int N, int K)
{
    __shared__ float As[32][68];
    __shared__ float Bs[64][68];
    const int t = threadIdx.x;
    const int row0 = blockIdx.x * 32;
    const int col0 = blockIdx.y * 64;
    const int tr = t & 7;
    const int tc = t >> 3;
    float acc[4][2] = {{0.f,0.f},{0.f,0.f},{0.f,0.f},{0.f,0.f}};

    for (int k0 = 0; k0 < K; k0 += 64) {
        {
            int r = t >> 3;
            int q = t & 7;
            const float* src = &A[(size_t)(row0 + r) * K + k0];
            #pragma unroll
            for (int it = 0; it < 2; ++it) {
                int kk = (q + it * 8) * 4;
                *(float4*)&As[r][kk] = *(const float4*)&src[kk];
            }
        }
        {
            int r = t >> 2;
            int q = t & 3;
            int n = col0 + r;
            #pragma unroll
            for (int it = 0; it < 4; ++it) {
                int kk = (q + it * 4) * 4;
                float4 v = {0.f, 0.f, 0.f, 0.f};
                if (n < N) v = *(const float4*)&Bm[(size_t)n * K + k0 + kk];
                *(float4*)&Bs[r][kk] = v;
            }
        }
        __syncthreads();
        #pragma unroll
        for (int k = 0; k < 64; k += 4) {
            float4 av[4], bv[2];
            #pragma unroll
            for (int i = 0; i < 4; ++i) av[i] = *(const float4*)&As[tr + 8*i][k];
            #pragma unroll
            for (int j = 0; j < 2; ++j) bv[j] = *(const float4*)&Bs[tc + 32*j][k];
            #pragma unroll
            for (int i = 0; i < 4; ++i)
                #pragma unroll
                for (int j = 0; j < 2; ++j)
                    acc[i][j] += av[i].x*bv[j].x + av[i].y*bv[j].y
                               + av[i].z*bv[j].z + av[i].w*bv[j].w;
        }
        __syncthreads();
    }

    #pragma unroll
    for (int i = 0; i < 4; ++i) {
        int r = row0 + tr + 8*i;
        #pragma unroll
        for (int j = 0; j < 2; ++j) {
            int c = col0 + tc + 32*j;
            if (c < N) C[(size_t)r * N + c] = acc[i][j] + bias[c];
        }
    }
}

__global__ __launch_bounds__(256) void gemm_bt(
    const float* __restrict__ A, const float* __restrict__ Bm,
    const float* __restrict__ bias, float* __restrict__ C,
    int N, int K)
{
    gemm_bt_body(A, Bm, bias, C, N, K);
}

__global__ __launch_bounds__(256) void gemm_bt_dual(
    const float* __restrict__ A,
    const float* __restrict__ B0, const float* __restrict__ bias0, float* __restrict__ C0,
    const float* __restrict__ B1, const float* __restrict__ bias1, float* __restrict__ C1,
    int N, int K)
{
    const float* Bm   = blockIdx.z ? B1    : B0;
    const float* bias = blockIdx.z ? bias1 : bias0;
    float*       C    = blockIdx.z ? C1    : C0;
    gemm_bt_body(A, Bm, bias, C, N, K);
}

// ---------------------------------------------------------------------------
// Prep: pack Whh (192x64 fp32) into f16 pairs (192x32 u32), both GRUs.
// ---------------------------------------------------------------------------
__global__ __launch_bounds__(256) void cvt_w16_kernel(
    const float* __restrict__ Whh_a, const float* __restrict__ Whh_b,
    unsigned* __restrict__ wa16, unsigned* __restrict__ wb16)
{
    int i = blockIdx.x * 256 + threadIdx.x;   // 0..6143
    if (i < GG * HH / 2) {
        float2 a = ((const float2*)Whh_a)[i];
        float2 b = ((const float2*)Whh_b)[i];
        f16x2 pa = __builtin_amdgcn_cvt_pkrtz(a.x, a.y);
        f16x2 pb = __builtin_amdgcn_cvt_pkrtz(b.x, b.y);
        wa16[i] = __builtin_bit_cast(unsigned, pa);
        wb16[i] = __builtin_bit_cast(unsigned, pb);
    }
}

// ---------------------------------------------------------------------------
// GRU scan (r20). EXACTLY r10's proven structure (best measured: 108.7us;
// 3 waves/chain, one gate per wave, fp32 math, native v_fma + readlane,
// lgkm-only barrier, double-buffered gh, remat-refetched weights) with ONE
// change: weights stored as f16 pairs. r10's residual stall: per-CU live
// weight set 48KB fp32 > 32KB L1 -> remat refetches thrash to L2 (~200+cyc)
// every step. f16 halves that to 24KB (L1-fits) and halves load count
// (8 uint4 vs 16 float4). Unpack via __half22float2 = 2 native
// v_cvt_f32_f16 (+~64 inst/step) — unlike r16/r17 the MAC stream stays
// native fp32 v_fma. Math in fp32; absmax -> ~0.0156 (r16-measured, <<0.24).
// ---------------------------------------------------------------------------
__global__ __launch_bounds__(192, 1)
__attribute__((amdgpu_waves_per_eu(1, 1)))
void gru_kernel(
    const float* __restrict__ xpa, const float* __restrict__ xpb,
    const unsigned* __restrict__ wa16, const unsigned* __restrict__ wb16,
    const float* __restrict__ bhh_a, const float* __restrict__ bhh_b,
    float* __restrict__ hs_a, float* __restrict__ hs_b)
{
    const int blk = blockIdx.x;
    const int b = blk >> 1;
    const int which = blk & 1;
    const float* xp    = which ? xpb   : xpa;
    const unsigned* wf = which ? wb16  : wa16;
    const float* bhh   = which ? bhh_b : bhh_a;
    float* hs          = which ? hs_b  : hs_a;

    const int t = threadIdx.x;       // 0..191
    const int g = t >> 6;            // gate: 0=r, 1=z, 2=n
    const int j = t & 63;

    __shared__ float gh_s[2][GG];

    // 64 f16 weights of row g*64+j as 8 NAMED uint4 SSA values (128B/lane).
    const uint4* wrow = (const uint4*)(wf + (size_t)(g * 64 + j) * 32);
    uint4 q0 = wrow[0], q1 = wrow[1], q2 = wrow[2], q3 = wrow[3];
    uint4 q4 = wrow[4], q5 = wrow[5], q6 = wrow[6], q7 = wrow[7];

    const float bh = bhh[g * 64 + j];

    const float* xrow = xp + (size_t)b * SS * GG;
    float* hrow = hs + (size_t)b * SS * HH;
    float hcur = 0.f;

    float xg = xrow[g * 64 + j];
    float xn = xrow[128 + j];

#define RL(v, k) __int_as_float(__builtin_amdgcn_readlane(__float_as_int(v), (k)))
#define BCH2(u) __builtin_bit_cast(__half2, (unsigned)(u))
#define DOT8(Q, c)                                              \
    {                                                           \
        float2 p0 = __half22float2(BCH2(Q.x));                  \
        float2 p1 = __half22float2(BCH2(Q.y));                  \
        float2 p2 = __half22float2(BCH2(Q.z));                  \
        float2 p3 = __half22float2(BCH2(Q.w));                  \
        a0 = fmaf(p0.x, RL(hcur, 8*(c) + 0), a0);               \
        a1 = fmaf(p0.y, RL(hcur, 8*(c) + 1), a1);               \
        a2 = fmaf(p1.x, RL(hcur, 8*(c) + 2), a2);               \
        a3 = fmaf(p1.y, RL(hcur, 8*(c) + 3), a3);               \
        a0 = fmaf(p2.x, RL(hcur, 8*(c) + 4), a0);               \
        a1 = fmaf(p2.y, RL(hcur, 8*(c) + 5), a1);               \
        a2 = fmaf(p3.x, RL(hcur, 8*(c) + 6), a2);               \
        a3 = fmaf(p3.y, RL(hcur, 8*(c) + 7), a3);               \
    }

    for (int s = 0; s < SS; ++s) {
        // Prefetch next step's xp (stays in flight across the lgkm-only
        // barrier; last iter over-reads into adjacent workspace — harmless).
        const float* nx = xrow + GG;
        float nxg = nx[g * 64 + j];
        float nxn = nx[128 + j];

        float a0 = bh, a1 = 0.f, a2 = 0.f, a3 = 0.f;
        DOT8(q0, 0) DOT8(q1, 1) DOT8(q2, 2) DOT8(q3, 3)
        DOT8(q4, 4) DOT8(q5, 5) DOT8(q6, 6) DOT8(q7, 7)
        float pre = (a0 + a1) + (a2 + a3);
        gh_s[s & 1][t] = (g < 2) ? (xg + pre) : pre;

        // LDS-only barrier: don't drain vmcnt.
        asm volatile("s_waitcnt lgkmcnt(0)" ::: "memory");
        __builtin_amdgcn_s_barrier();
        asm volatile("" ::: "memory");

        float ghr = gh_s[s & 1][j];
        float ghz = gh_s[s & 1][64 + j];
        float ghn = gh_s[s & 1][128 + j];
        float r = sigmoid_f(ghr);
        float z = sigmoid_f(ghz);
        float n = tanh_f(xn + r * ghn);
        hcur = fmaf(z, hcur - n, n);
        if (g == 0) hrow[j] = hcur;

        xg = nxg; xn = nxn;
        xrow += GG;
        hrow += HH;
    }
#undef DOT8
#undef BCH2
#undef RL
}

// ---------------------------------------------------------------------------
// FUSED attn_val + scanA. One block per (batch, 16-row tile).
// ---------------------------------------------------------------------------
__global__ __launch_bounds__(128) void attn_scanA_kernel(
    const float* __restrict__ h_alpha, const float* __restrict__ h_beta,
    const float* __restrict__ emb, const float* __restrict__ M,
    const float* __restrict__ Wa, const float* __restrict__ ba,
    const float* __restrict__ Wb, const float* __restrict__ bb,
    float* __restrict__ val, float* __restrict__ wj,
    float* __restrict__ tsum, float* __restrict__ wsum)
{
    const int b = blockIdx.x, tt = blockIdx.y;
    const int t = threadIdx.x;       // 0..127
    const int j0 = tt * 16;
    __shared__ float hb_s[HH];
    __shared__ float wj_s;

    const float bbt = bb[t];
    const float4* wrow = (const float4*)&Wb[(size_t)t * HH];

    float ts = 0.f;
    float ws = 0.f;

    for (int jj = 0; jj < 16; ++jj) {
        const int row = b * SS + j0 + jj;
        if (t < 64) {
            hb_s[t] = h_beta[(size_t)row * HH + t];
            float p = h_alpha[(size_t)row * HH + t] * Wa[t];
            #pragma unroll
            for (int off = 32; off > 0; off >>= 1) p += __shfl_down(p, off);
            if (t == 0) {
                float a = __expf(p + ba[0]) * M[row];
                wj_s = a;
                wj[row] = a;
            }
        }
        __syncthreads();

        float acc = bbt;
        #pragma unroll
        for (int k = 0; k < 16; ++k) {
            float4 w4 = wrow[k];
            float4 h4 = *(const float4*)&hb_s[k * 4];
            acc += w4.x*h4.x + w4.y*h4.y + w4.z*h4.z + w4.w*h4.w;
        }
        float v = tanh_f(acc) * emb[(size_t)row * EE + t] * wj_s;
        val[(size_t)row * EE + t] = v;
        ts += v;
        if (t == 0) ws += wj_s;
        __syncthreads();   // hb_s/wj_s reused next row
    }

    tsum[((size_t)(b * TT + tt)) * EE + t] = ts;
    if (t == 0) wsum[b * TT + tt] = ws;
}

// ---------------------------------------------------------------------------
// FUSED scanB + proj + cur-partial. One block per (batch, 16-row tile);
// wtd stays in LDS; each block atomicAdds its 16-row partial of
// cur_output[b,l] (out_cur zeroed by hipMemsetAsync before launch).
// ---------------------------------------------------------------------------
__global__ __launch_bounds__(128) void scanB_proj_kernel(
    const float* __restrict__ val, const float* __restrict__ wj,
    const float* __restrict__ tsum, const float* __restrict__ wsum,
    const float* __restrict__ Wp, const float* __restrict__ bp,
    const float* __restrict__ M, const float* __restrict__ curM,
    float* __restrict__ out, float* __restrict__ out_cur)
{
    const int b = blockIdx.x, tt = blockIdx.y;
    const int t = threadIdx.x;       // 0..127  (= e for the scan phase)
    const int j0 = tt * 16;

    __shared__ float wtd_s[16][132];
    __shared__ float wp_s[8][132];
    __shared__ float red_s[16][8];

    // beyond-tile suffix
    float se = 0.f;
    for (int t2 = tt + 1; t2 < TT; ++t2)
        se += tsum[((size_t)(b * TT + t2)) * EE + t];
    float d = 1e-10f;
    for (int t2 = tt + 1; t2 < TT; ++t2)
        d += wsum[b * TT + t2];

    // in-tile suffix (16 steps), results stay in LDS
    for (int jj = 15; jj >= 0; --jj) {
        size_t idx = ((size_t)(b * SS + j0 + jj)) * EE + t;
        se += val[idx];
        d += wj[b * SS + j0 + jj];
        wtd_s[jj][t] = se / d;
    }

    // stage Wp (8 x 128): 256 float4 total, 2 per thread
    #pragma unroll
    for (int it = 0; it < 2; ++it) {
        int idx = t + it * 128;      // 0..255
        int r = idx >> 5;            // 0..7
        int c = idx & 31;            // 0..31
        *(float4*)&wp_s[r][c * 4] = *(const float4*)&Wp[(size_t)r * EE + c * 4];
    }
    __syncthreads();

    // projection: thread = (row r, output l)
    const int r = t >> 3, l = t & 7;
    float acc = 0.f;
    #pragma unroll
    for (int i = 0; i < 32; ++i) {
        float4 a = *(const float4*)&wtd_s[r][i * 4];
        float4 w = *(const float4*)&wp_s[l][i * 4];
        acc += a.x*w.x + a.y*w.y + a.z*w.z + a.w*w.w;
    }
    const int row = b * SS + j0 + r;
    float ov = (acc + bp[l]) * M[row];
    out[(size_t)row * LL + l] = ov;

    // cur partial: sum over this tile's 16 rows for each l
    red_s[r][l] = ov * curM[row];
    __syncthreads();
    if (t < 8) {
        float sum = 0.f;
        #pragma unroll
        for (int r2 = 0; r2 < 16; ++r2) sum += red_s[r2][t];
        atomicAdd(&out_cur[b * LL + t], sum);
    }
}

// ---------------------------------------------------------------------------
extern "C" void kernel_launch(void* const* d_in, const int* in_sizes, int n_in,
                              void* d_out, int out_size, void* d_ws, size_t ws_size,
                              hipStream_t stream)
{
    const float* X       = (const float*)d_in[0];
    const float* M       = (const float*)d_in[1];
    const float* cur_M   = (const float*)d_in[2];
    const float* W_embed = (const float*)d_in[3];
    const float* b_embed = (const float*)d_in[4];
    const float* Wih_a   = (const float*)d_in[5];
    const float* Whh_a   = (const float*)d_in[6];
    const float* bih_a   = (const float*)d_in[7];
    const float* bhh_a   = (const float*)d_in[8];
    const float* Wih_b   = (const float*)d_in[9];
    const float* Whh_b   = (const float*)d_in[10];
    const float* bih_b   = (const float*)d_in[11];
    const float* bhh_b   = (const float*)d_in[12];
    const float* Wb      = (const float*)d_in[13];
    const float* bb      = (const float*)d_in[14];
    const float* Wa      = (const float*)d_in[15];
    const float* ba      = (const float*)d_in[16];
    const float* Wp      = (const float*)d_in[17];
    const float* bp      = (const float*)d_in[18];
    float* out = (float*)d_out;
    float* out_cur = out + (size_t)BB * SS * LL;

    float* ws  = (float*)d_ws;
    float* emb = ws;                          // B*S*E
    float* xpa = emb + (size_t)BB*SS*EE;      // B*S*192
    float* xpb = xpa + (size_t)BB*SS*GG;
    float* ha  = xpb + (size_t)BB*SS*GG;      // B*S*H
    float* hb  = ha  + (size_t)BB*SS*HH;
    float* val = hb  + (size_t)BB*SS*HH;      // B*S*E
    float* wjv = val + (size_t)BB*SS*EE;      // B*S
    float* tsum = wjv + (size_t)BB*SS;        // B*TT*E
    float* wsum = tsum + (size_t)BB*TT*EE;    // B*TT
    unsigned* wa16 = (unsigned*)(wsum + (size_t)BB*TT);  // 6144 u32
    unsigned* wb16 = wa16 + (size_t)GG*HH/2;             // 6144 u32

    const int ROWS = BB * SS;                 // 4096

    hipMemsetAsync(out_cur, 0, (size_t)BB * LL * sizeof(float), stream);
    cvt_w16_kernel<<<24, 256, 0, stream>>>(Whh_a, Whh_b, wa16, wb16);
    gemm_bt<<<dim3(ROWS/32, EE/64), 256, 0, stream>>>(X, W_embed, b_embed, emb, EE, FF);
    gemm_bt_dual<<<dim3(ROWS/32, (GG+63)/64, 2), 256, 0, stream>>>(
        emb, Wih_a, bih_a, xpa, Wih_b, bih_b, xpb, GG, EE);
    gru_kernel<<<32, 192, 0, stream>>>(xpa, xpb, wa16, wb16, bhh_a, bhh_b, ha, hb);
    attn_scanA_kernel<<<dim3(BB, TT), 128, 0, stream>>>(
        ha, hb, emb, M, Wa, ba, Wb, bb, val, wjv, tsum, wsum);
    scanB_proj_kernel<<<dim3(BB, TT), 128, 0, stream>>>(
        val, wjv, tsum, wsum, Wp, bp, M, cur_M, out, out_cur);
}

// Round 21
// 173.310 us; speedup vs baseline: 1.5450x; 1.1104x over previous
//
#include <hip/hip_runtime.h>
#include <math.h>

#define BB 16
#define SS 256
#define FF 512
#define EE 128
#define HH 64
#define GG 192  // 3H
#define LL 8
#define TT 16   // scan tile count (SS/16)

__device__ __forceinline__ float sigmoid_f(float x) {
    return 1.0f / (1.0f + __expf(-x));
}
__device__ __forceinline__ float tanh_f(float x) {
    return 1.0f - 2.0f / (1.0f + __expf(2.0f * x));
}

// ---------------------------------------------------------------------------
// Generic C[m,n] = sum_k A[m,k] * Bm[n,k] + bias[n]
// ---------------------------------------------------------------------------
__device__ __forceinline__ void gemm_bt_body(
    const float* __restrict__ A, const float* __restrict__ Bm,
    const float* __restrict__ bias, float* __restrict__ C,
    int N, int K)
{
    __shared__ float As[32][68];
    __shared__ float Bs[64][68];
    const int t = threadIdx.x;
    const int row0 = blockIdx.x * 32;
    const int col0 = blockIdx.y * 64;
    const int tr = t & 7;
    const int tc = t >> 3;
    float acc[4][2] = {{0.f,0.f},{0.f,0.f},{0.f,0.f},{0.f,0.f}};

    for (int k0 = 0; k0 < K; k0 += 64) {
        {
            int r = t >> 3;
            int q = t & 7;
            const float* src = &A[(size_t)(row0 + r) * K + k0];
            #pragma unroll
            for (int it = 0; it < 2; ++it) {
                int kk = (q + it * 8) * 4;
                *(float4*)&As[r][kk] = *(const float4*)&src[kk];
            }
        }
        {
            int r = t >> 2;
            int q = t & 3;
            int n = col0 + r;
            #pragma unroll
            for (int it = 0; it < 4; ++it) {
                int kk = (q + it * 4) * 4;
                float4 v = {0.f, 0.f, 0.f, 0.f};
                if (n < N) v = *(const float4*)&Bm[(size_t)n * K + k0 + kk];
                *(float4*)&Bs[r][kk] = v;
            }
        }
        __syncthreads();
        #pragma unroll
        for (int k = 0; k < 64; k += 4) {
            float4 av[4], bv[2];
            #pragma unroll
            for (int i = 0; i < 4; ++i) av[i] = *(const float4*)&As[tr + 8*i][k];
            #pragma unroll
            for (int j = 0; j < 2; ++j) bv[j] = *(const float4*)&Bs[tc + 32*j][k];
            #pragma unroll
            for (int i = 0; i < 4; ++i)
                #pragma unroll
                for (int j = 0; j < 2; ++j)
                    acc[i][j] += av[i].x*bv[j].x + av[i].y*bv[j].y
                               + av[i].z*bv[j].z + av[i].w*bv[j].w;
        }
        __syncthreads();
    }

    #pragma unroll
    for (int i = 0; i < 4; ++i) {
        int r = row0 + tr + 8*i;
        #pragma unroll
        for (int j = 0; j < 2; ++j) {
            int c = col0 + tc + 32*j;
            if (c < N) C[(size_t)r * N + c] = acc[i][j] + bias[c];
        }
    }
}

__global__ __launch_bounds__(256) void gemm_bt(
    const float* __restrict__ A, const float* __restrict__ Bm,
    const float* __restrict__ bias, float* __restrict__ C,
    int N, int K)
{
    gemm_bt_body(A, Bm, bias, C, N, K);
}

__global__ __launch_bounds__(256) void gemm_bt_dual(
    const float* __restrict__ A,
    const float* __restrict__ B0, const float* __restrict__ bias0, float* __restrict__ C0,
    const float* __restrict__ B1, const float* __restrict__ bias1, float* __restrict__ C1,
    int N, int K)
{
    const float* Bm   = blockIdx.z ? B1    : B0;
    const float* bias = blockIdx.z ? bias1 : bias0;
    float*       C    = blockIdx.z ? C1    : C0;
    gemm_bt_body(A, Bm, bias, C, N, K);
}

// ---------------------------------------------------------------------------
// GRU scan — r10 exact (measured floor: 108.7us across 15 variants).
// 3 waves/chain (one gate per wave), fp32 math, weights as named float4 SSA
// (remat-refetched from L1/L2 — measured cheaper than scratch r5-r9, pin
// r11, LDS r12, AGPR r14, f16 r16/r17/r20, 6-wave r8, 2-chain r18, MFMA
// r19), lgkm-only barrier, double-buffered gh. ~1019 cyc/step = issue +
// pipelined-L1 + barrier + LDS + gates; latency-bound sequential chain.
// ---------------------------------------------------------------------------
__global__ __launch_bounds__(192, 1)
__attribute__((amdgpu_waves_per_eu(1, 1)))
void gru_kernel(
    const float* __restrict__ xpa, const float* __restrict__ xpb,
    const float* __restrict__ Whh_a, const float* __restrict__ bhh_a,
    const float* __restrict__ Whh_b, const float* __restrict__ bhh_b,
    float* __restrict__ hs_a, float* __restrict__ hs_b)
{
    const int blk = blockIdx.x;
    const int b = blk >> 1;
    const int which = blk & 1;
    const float* xp  = which ? xpb   : xpa;
    const float* Whh = which ? Whh_b : Whh_a;
    const float* bhh = which ? bhh_b : bhh_a;
    float* hs        = which ? hs_b  : hs_a;

    const int t = threadIdx.x;       // 0..191
    const int g = t >> 6;            // gate: 0=r, 1=z, 2=n
    const int j = t & 63;

    __shared__ float gh_s[2][GG];

    const float4* wrow = (const float4*)&Whh[(size_t)(g * 64 + j) * HH];
    float4 w0  = wrow[0],  w1  = wrow[1],  w2  = wrow[2],  w3  = wrow[3];
    float4 w4  = wrow[4],  w5  = wrow[5],  w6  = wrow[6],  w7  = wrow[7];
    float4 w8  = wrow[8],  w9  = wrow[9],  w10 = wrow[10], w11 = wrow[11];
    float4 w12 = wrow[12], w13 = wrow[13], w14 = wrow[14], w15 = wrow[15];

    const float bh = bhh[g * 64 + j];

    const float* xrow = xp + (size_t)b * SS * GG;
    float* hrow = hs + (size_t)b * SS * HH;
    float hcur = 0.f;

    float xg = xrow[g * 64 + j];
    float xn = xrow[128 + j];

#define RL(v, k) __int_as_float(__builtin_amdgcn_readlane(__float_as_int(v), (k)))
#define DOT4(W, i)                                  \
    a0 = fmaf(W.x, RL(hcur, 4*(i) + 0), a0);        \
    a1 = fmaf(W.y, RL(hcur, 4*(i) + 1), a1);        \
    a2 = fmaf(W.z, RL(hcur, 4*(i) + 2), a2);        \
    a3 = fmaf(W.w, RL(hcur, 4*(i) + 3), a3);

    for (int s = 0; s < SS; ++s) {
        const float* nx = xrow + GG;
        float nxg = nx[g * 64 + j];
        float nxn = nx[128 + j];

        float a0 = bh, a1 = 0.f, a2 = 0.f, a3 = 0.f;
        DOT4(w0, 0)   DOT4(w1, 1)   DOT4(w2, 2)   DOT4(w3, 3)
        DOT4(w4, 4)   DOT4(w5, 5)   DOT4(w6, 6)   DOT4(w7, 7)
        DOT4(w8, 8)   DOT4(w9, 9)   DOT4(w10, 10) DOT4(w11, 11)
        DOT4(w12, 12) DOT4(w13, 13) DOT4(w14, 14) DOT4(w15, 15)
        float pre = (a0 + a1) + (a2 + a3);
        gh_s[s & 1][t] = (g < 2) ? (xg + pre) : pre;

        // LDS-only barrier: don't drain vmcnt.
        asm volatile("s_waitcnt lgkmcnt(0)" ::: "memory");
        __builtin_amdgcn_s_barrier();
        asm volatile("" ::: "memory");

        float ghr = gh_s[s & 1][j];
        float ghz = gh_s[s & 1][64 + j];
        float ghn = gh_s[s & 1][128 + j];
        float r = sigmoid_f(ghr);
        float z = sigmoid_f(ghz);
        float n = tanh_f(xn + r * ghn);
        hcur = fmaf(z, hcur - n, n);
        if (g == 0) hrow[j] = hcur;

        xg = nxg; xn = nxn;
        xrow += GG;
        hrow += HH;
    }
#undef DOT4
#undef RL
}

// ---------------------------------------------------------------------------
// FUSED attn_val + scanA. One block per (batch, 16-row tile).
// ---------------------------------------------------------------------------
__global__ __launch_bounds__(128) void attn_scanA_kernel(
    const float* __restrict__ h_alpha, const float* __restrict__ h_beta,
    const float* __restrict__ emb, const float* __restrict__ M,
    const float* __restrict__ Wa, const float* __restrict__ ba,
    const float* __restrict__ Wb, const float* __restrict__ bb,
    float* __restrict__ val, float* __restrict__ wj,
    float* __restrict__ tsum, float* __restrict__ wsum)
{
    const int b = blockIdx.x, tt = blockIdx.y;
    const int t = threadIdx.x;       // 0..127
    const int j0 = tt * 16;
    __shared__ float hb_s[HH];
    __shared__ float wj_s;

    const float bbt = bb[t];
    const float4* wrow = (const float4*)&Wb[(size_t)t * HH];

    float ts = 0.f;
    float ws = 0.f;

    for (int jj = 0; jj < 16; ++jj) {
        const int row = b * SS + j0 + jj;
        if (t < 64) {
            hb_s[t] = h_beta[(size_t)row * HH + t];
            float p = h_alpha[(size_t)row * HH + t] * Wa[t];
            #pragma unroll
            for (int off = 32; off > 0; off >>= 1) p += __shfl_down(p, off);
            if (t == 0) {
                float a = __expf(p + ba[0]) * M[row];
                wj_s = a;
                wj[row] = a;
            }
        }
        __syncthreads();

        float acc = bbt;
        #pragma unroll
        for (int k = 0; k < 16; ++k) {
            float4 w4 = wrow[k];
            float4 h4 = *(const float4*)&hb_s[k * 4];
            acc += w4.x*h4.x + w4.y*h4.y + w4.z*h4.z + w4.w*h4.w;
        }
        float v = tanh_f(acc) * emb[(size_t)row * EE + t] * wj_s;
        val[(size_t)row * EE + t] = v;
        ts += v;
        if (t == 0) ws += wj_s;
        __syncthreads();   // hb_s/wj_s reused next row
    }

    tsum[((size_t)(b * TT + tt)) * EE + t] = ts;
    if (t == 0) wsum[b * TT + tt] = ws;
}

// ---------------------------------------------------------------------------
// FUSED scanB + proj. One block per (batch, 16-row tile); wtd stays in LDS.
// ---------------------------------------------------------------------------
__global__ __launch_bounds__(128) void scanB_proj_kernel(
    const float* __restrict__ val, const float* __restrict__ wj,
    const float* __restrict__ tsum, const float* __restrict__ wsum,
    const float* __restrict__ Wp, const float* __restrict__ bp,
    const float* __restrict__ M, float* __restrict__ out)
{
    const int b = blockIdx.x, tt = blockIdx.y;
    const int t = threadIdx.x;       // 0..127  (= e for the scan phase)
    const int j0 = tt * 16;

    __shared__ float wtd_s[16][132];
    __shared__ float wp_s[8][132];

    // beyond-tile suffix
    float se = 0.f;
    for (int t2 = tt + 1; t2 < TT; ++t2)
        se += tsum[((size_t)(b * TT + t2)) * EE + t];
    float d = 1e-10f;
    for (int t2 = tt + 1; t2 < TT; ++t2)
        d += wsum[b * TT + t2];

    // in-tile suffix (16 steps), results stay in LDS
    for (int jj = 15; jj >= 0; --jj) {
        size_t idx = ((size_t)(b * SS + j0 + jj)) * EE + t;
        se += val[idx];
        d += wj[b * SS + j0 + jj];
        wtd_s[jj][t] = se / d;
    }

    // stage Wp (8 x 128): 256 float4 total, 2 per thread
    #pragma unroll
    for (int it = 0; it < 2; ++it) {
        int idx = t + it * 128;      // 0..255
        int r = idx >> 5;            // 0..7
        int c = idx & 31;            // 0..31
        *(float4*)&wp_s[r][c * 4] = *(const float4*)&Wp[(size_t)r * EE + c * 4];
    }
    __syncthreads();

    // projection: thread = (row r, output l)
    const int r = t >> 3, l = t & 7;
    float acc = 0.f;
    #pragma unroll
    for (int i = 0; i < 32; ++i) {
        float4 a = *(const float4*)&wtd_s[r][i * 4];
        float4 w = *(const float4*)&wp_s[l][i * 4];
        acc += a.x*w.x + a.y*w.y + a.z*w.z + a.w*w.w;
    }
    const int row = b * SS + j0 + r;
    out[(size_t)row * LL + l] = (acc + bp[l]) * M[row];
}

// ---------------------------------------------------------------------------
// cur_output[b,l] = sum_s all_output[b,s,l] * cur_M[b,s]
// ---------------------------------------------------------------------------
__global__ __launch_bounds__(256) void cur_kernel(
    const float* __restrict__ out_all, const float* __restrict__ curM,
    float* __restrict__ out_cur)
{
    const int b = blockIdx.x;
    const int t = threadIdx.x;
    const int l = t & 7, c = t >> 3;
    float p = 0.f;
    #pragma unroll
    for (int k = 0; k < 8; ++k) {
        int s = c + k * 32;
        p += out_all[((size_t)(b * SS + s)) * LL + l] * curM[b * SS + s];
    }
    __shared__ float red[32][9];
    red[c][l] = p;
    __syncthreads();
    if (t < 8) {
        float sum = 0.f;
        for (int c2 = 0; c2 < 32; ++c2) sum += red[c2][t];
        out_cur[b * LL + t] = sum;
    }
}

// ---------------------------------------------------------------------------
extern "C" void kernel_launch(void* const* d_in, const int* in_sizes, int n_in,
                              void* d_out, int out_size, void* d_ws, size_t ws_size,
                              hipStream_t stream)
{
    const float* X       = (const float*)d_in[0];
    const float* M       = (const float*)d_in[1];
    const float* cur_M   = (const float*)d_in[2];
    const float* W_embed = (const float*)d_in[3];
    const float* b_embed = (const float*)d_in[4];
    const float* Wih_a   = (const float*)d_in[5];
    const float* Whh_a   = (const float*)d_in[6];
    const float* bih_a   = (const float*)d_in[7];
    const float* bhh_a   = (const float*)d_in[8];
    const float* Wih_b   = (const float*)d_in[9];
    const float* Whh_b   = (const float*)d_in[10];
    const float* bih_b   = (const float*)d_in[11];
    const float* bhh_b   = (const float*)d_in[12];
    const float* Wb      = (const float*)d_in[13];
    const float* bb      = (const float*)d_in[14];
    const float* Wa      = (const float*)d_in[15];
    const float* ba      = (const float*)d_in[16];
    const float* Wp      = (const float*)d_in[17];
    const float* bp      = (const float*)d_in[18];
    float* out = (float*)d_out;

    float* ws  = (float*)d_ws;
    float* emb = ws;                          // B*S*E
    float* xpa = emb + (size_t)BB*SS*EE;      // B*S*192
    float* xpb = xpa + (size_t)BB*SS*GG;
    float* ha  = xpb + (size_t)BB*SS*GG;      // B*S*H
    float* hb  = ha  + (size_t)BB*SS*HH;
    float* val = hb  + (size_t)BB*SS*HH;      // B*S*E
    float* wjv = val + (size_t)BB*SS*EE;      // B*S
    float* tsum = wjv + (size_t)BB*SS;        // B*TT*E
    float* wsum = tsum + (size_t)BB*TT*EE;    // B*TT

    const int ROWS = BB * SS;                 // 4096

    gemm_bt<<<dim3(ROWS/32, EE/64), 256, 0, stream>>>(X, W_embed, b_embed, emb, EE, FF);
    gemm_bt_dual<<<dim3(ROWS/32, (GG+63)/64, 2), 256, 0, stream>>>(
        emb, Wih_a, bih_a, xpa, Wih_b, bih_b, xpb, GG, EE);
    gru_kernel<<<32, 192, 0, stream>>>(xpa, xpb, Whh_a, bhh_a, Whh_b, bhh_b, ha, hb);
    attn_scanA_kernel<<<dim3(BB, TT), 128, 0, stream>>>(
        ha, hb, emb, M, Wa, ba, Wb, bb, val, wjv, tsum, wsum);
    scanB_proj_kernel<<<dim3(BB, TT), 128, 0, stream>>>(
        val, wjv, tsum, wsum, Wp, bp, M, out);
    cur_kernel<<<BB, 256, 0, stream>>>(out, cur_M, out + (size_t)BB*SS*LL);
}